// Round 9
// baseline (424.778 us; speedup 1.0000x reference)
//
#include <hip/hip_runtime.h>
#include <stdint.h>

// SparseMoE: B=4,S=2048,D=1024,E=8,H=2048, top-k=2.
// Outputs (concat, float32): final_output[8192*1024], top_k_indices[8192*2] (as floats), aux_loss[1].

#define NTOK   8192
#define DIM    1024
#define NEXP   8
#define HID    2048
#define OUT_MAIN (NTOK * DIM)          // 8388608
#define IDX_OFF  OUT_MAIN
#define AUX_OFF  (OUT_MAIN + NTOK * 2) // 8404992
#define MAXBLK 144                     // >= 128 + 7 worst-case 128-row m-blocks; 144 = 18*8

typedef __attribute__((ext_vector_type(8))) short short8;
typedef __attribute__((ext_vector_type(4))) float floatx4;

__device__ __forceinline__ unsigned short f2bf(float f) {
  unsigned int b = __float_as_uint(f);
  b += 0x7FFFu + ((b >> 16) & 1u);      // RNE; inputs finite
  return (unsigned short)(b >> 16);
}

// ---------------- gating: logits (fp64 acc), top-2, masked softmax, scatter, xb=bf16(x) ---
__global__ __launch_bounds__(1024) void k_gating(
    const float* __restrict__ x, const float* __restrict__ gate_w,
    const float* __restrict__ gate_b, const float* __restrict__ noise,
    float* __restrict__ out, int* __restrict__ counts,
    int* __restrict__ lists_tok, float* __restrict__ lists_p,
    float* __restrict__ probs_all, unsigned short* __restrict__ xb)
{
  const int lane = threadIdx.x & 63;
  const int wv   = threadIdx.x >> 6;              // 0..15
  const int t    = blockIdx.x * 16 + wv;          // one token per wave
  const float* xr = x + (size_t)t * DIM;

  __shared__ int   cnt[NEXP];
  __shared__ int   base[NEXP];
  __shared__ int   s_e[32];
  __shared__ int   s_pos[32];
  __shared__ float s_p[32];
  if (threadIdx.x < NEXP) cnt[threadIdx.x] = 0;

  double acc[NEXP] = {0,0,0,0,0,0,0,0};
  #pragma unroll
  for (int jj = 0; jj < 4; ++jj) {
    const int d0 = lane * 4 + jj * 256;
    const float4 xv = *(const float4*)(xr + d0);
    const float xs[4] = {xv.x, xv.y, xv.z, xv.w};
    unsigned short xbq[4];
    #pragma unroll
    for (int c = 0; c < 4; ++c) {
      const float4 g0 = *(const float4*)(gate_w + (size_t)(d0 + c) * NEXP);
      const float4 g1 = *(const float4*)(gate_w + (size_t)(d0 + c) * NEXP + 4);
      const double xd = (double)xs[c];
      acc[0] += xd * (double)g0.x; acc[1] += xd * (double)g0.y;
      acc[2] += xd * (double)g0.z; acc[3] += xd * (double)g0.w;
      acc[4] += xd * (double)g1.x; acc[5] += xd * (double)g1.y;
      acc[6] += xd * (double)g1.z; acc[7] += xd * (double)g1.w;
      xbq[c] = f2bf(xs[c]);
    }
    ushort4 q; q.x = xbq[0]; q.y = xbq[1]; q.z = xbq[2]; q.w = xbq[3];
    *(ushort4*)(xb + (size_t)t * DIM + d0) = q;
  }
  #pragma unroll
  for (int e = 0; e < NEXP; ++e) {
    #pragma unroll
    for (int off = 32; off; off >>= 1) acc[e] += __shfl_xor(acc[e], off);
  }
  __syncthreads();                                 // cnt[] initialized
  if (lane == 0) {
    double l[NEXP];
    #pragma unroll
    for (int e = 0; e < NEXP; ++e)
      l[e] = acc[e] + (double)gate_b[e] + 0.01 * (double)noise[(size_t)t * NEXP + e];
    int i1 = 0; double v1 = l[0];
    #pragma unroll
    for (int e = 1; e < NEXP; ++e) if (l[e] > v1) { v1 = l[e]; i1 = e; }
    int i2 = (i1 == 0) ? 1 : 0; double v2 = l[i2];
    #pragma unroll
    for (int e = 0; e < NEXP; ++e) if (e != i1 && l[e] > v2) { v2 = l[e]; i2 = e; }
    float pr[NEXP]; float Z = 0.f;
    #pragma unroll
    for (int e = 0; e < NEXP; ++e) {
      const float a = (l[e] >= v2) ? (float)(l[e] - v1) : -1.0e9f;
      pr[e] = __expf(a); Z += pr[e];
    }
    const float rz = 1.0f / Z;
    #pragma unroll
    for (int e = 0; e < NEXP; ++e) {
      pr[e] *= rz;
      probs_all[(size_t)t * NEXP + e] = pr[e];
    }
    out[(size_t)IDX_OFF + t * 2]     = (float)i1;
    out[(size_t)IDX_OFF + t * 2 + 1] = (float)i2;
    const int p1 = atomicAdd(&cnt[i1], 1);
    const int p2 = atomicAdd(&cnt[i2], 1);
    s_e[wv * 2]     = i1; s_pos[wv * 2]     = p1; s_p[wv * 2]     = pr[i1];
    s_e[wv * 2 + 1] = i2; s_pos[wv * 2 + 1] = p2; s_p[wv * 2 + 1] = pr[i2];
  }
  __syncthreads();
  if (threadIdx.x < NEXP) base[threadIdx.x] = atomicAdd(&counts[threadIdx.x], cnt[threadIdx.x]);
  __syncthreads();
  if (lane == 0) {
    #pragma unroll
    for (int k = 0; k < 2; ++k) {
      const int ee  = s_e[wv * 2 + k];
      const int pos = base[ee] + s_pos[wv * 2 + k];
      lists_tok[ee * NTOK + pos] = t;
      lists_p[ee * NTOK + pos]   = s_p[wv * 2 + k];
    }
  }
}

// ---------------- meta: offsets + balanced XCD-local table (thread 0) + aux loss (all) --
// 128-row m-granularity. HW assigns XCD = linear_block_id % 8; gridDim.x=144 (≡0 mod 8)
// -> XCD = bx%8 for all by. Class c = pos%8 gets a CONTIGUOUS run of valid entries
// (expert/B-slice L2 locality) partitioned balanced over the VALID count; invalid = -1.
__global__ __launch_bounds__(256) void k_meta(
    const int* __restrict__ counts, int* __restrict__ offs,
    int* __restrict__ tbl_e, int* __restrict__ tbl_m, int* __restrict__ nblk,
    const float* __restrict__ probs_all, float* __restrict__ out)
{
  if (threadIdx.x == 0) {
    int a = 0;
    #pragma unroll
    for (int e = 0; e < NEXP; ++e) { offs[e] = a; a += counts[e]; }
    offs[NEXP] = a;
    int ent_e[MAXBLK], ent_m[MAXBLK];
    int nb = 0;
    for (int e = 0; e < NEXP; ++e) {
      const int nbe = (counts[e] + 127) >> 7;
      for (int m = 0; m < nbe; ++m) { ent_e[nb] = e; ent_m[nb] = m << 7; ++nb; }
    }
    nblk[0] = nb;
    for (int p = 0; p < MAXBLK; ++p) { tbl_e[p] = -1; tbl_m[p] = 0; }
    const int q = nb >> 3, r = nb & 7;
    for (int c = 0; c < 8; ++c) {
      const int cc    = q + (c < r ? 1 : 0);          // <= 18
      const int start = c * q + (c < r ? c : r);
      for (int t = 0; t < cc; ++t) {
        const int pos = c + (t << 3);                 // pos%8 == c, pos < 144
        tbl_e[pos] = ent_e[start + t];
        tbl_m[pos] = ent_m[start + t];
      }
    }
  }
  // aux loss (all 256 threads)
  float p[NEXP] = {0,0,0,0,0,0,0,0};
  for (int t = threadIdx.x; t < NTOK; t += 256) {
    const float4 a = *(const float4*)(probs_all + (size_t)t * NEXP);
    const float4 b = *(const float4*)(probs_all + (size_t)t * NEXP + 4);
    p[0] += a.x; p[1] += a.y; p[2] += a.z; p[3] += a.w;
    p[4] += b.x; p[5] += b.y; p[6] += b.z; p[7] += b.w;
  }
  #pragma unroll
  for (int e = 0; e < NEXP; ++e) {
    #pragma unroll
    for (int off = 32; off; off >>= 1) p[e] += __shfl_xor(p[e], off);
  }
  __shared__ float red[4][NEXP];
  const int lane = threadIdx.x & 63, wv = threadIdx.x >> 6;
  if (lane == 0) {
    #pragma unroll
    for (int e = 0; e < NEXP; ++e) red[wv][e] = p[e];
  }
  __syncthreads();
  if (threadIdx.x == 0) {
    float usage[NEXP], s = 0.f;
    #pragma unroll
    for (int e = 0; e < NEXP; ++e) {
      usage[e] = red[0][e] + red[1][e] + red[2][e] + red[3][e];
      s += usage[e];
    }
    float imp[NEXP], mean = 0.f, var = 0.f;
    #pragma unroll
    for (int e = 0; e < NEXP; ++e) { imp[e] = usage[e] / s; mean += imp[e]; }
    mean *= 0.125f;
    #pragma unroll
    for (int e = 0; e < NEXP; ++e) { const float d = imp[e] - mean; var += d * d; }
    var *= 0.125f;
    out[AUX_OFF] = sqrtf(var) / (mean + 1e-10f);
  }
}

// ---------------- weight transpose+convert: in[e][r][c] fp32 -> out[e][c-c0][r-r0] bf16 ---
__global__ __launch_bounds__(256) void k_tr(
    const float* __restrict__ in, unsigned short* __restrict__ out,
    int in_ld, size_t in_estride, int r0, int c0,
    int out_ld, size_t out_estride)
{
  const int e  = blockIdx.z;
  const int tr = blockIdx.x << 6;
  const int tc = blockIdx.y << 6;
  const int tid = threadIdx.x;
  __shared__ float t[64][65];
  const float* src = in + (size_t)e * in_estride + (size_t)(r0 + tr) * in_ld + (c0 + tc);
  #pragma unroll
  for (int p = 0; p < 4; ++p) {
    const int r  = (p << 4) + (tid >> 4);
    const int c4 = (tid & 15) << 2;
    const float4 v = *(const float4*)(src + (size_t)r * in_ld + c4);
    t[r][c4] = v.x; t[r][c4 + 1] = v.y; t[r][c4 + 2] = v.z; t[r][c4 + 3] = v.w;
  }
  __syncthreads();
  unsigned short* dst = out + (size_t)e * out_estride + (size_t)tc * out_ld + tr;
  #pragma unroll
  for (int p = 0; p < 4; ++p) {
    const int c  = (p << 4) + (tid >> 4);
    const int r4 = (tid & 15) << 2;
    ushort4 q;
    q.x = f2bf(t[r4][c]);     q.y = f2bf(t[r4 + 1][c]);
    q.z = f2bf(t[r4 + 2][c]); q.w = f2bf(t[r4 + 3][c]);
    *(ushort4*)(dst + (size_t)c * out_ld + r4) = q;
  }
}

// ---------------- grouped MFMA GEMM: 128x128 tile, 4 waves, BK=32, counted-vmcnt pipe ---
// m97-geometry port of the r3-verified loop. Rationale (r8 arithmetic): 256²/16-wave
// blocks = 1/CU -> every barrier idles the whole CU (13.1k cyc/K-tile vs ~5.6k of work;
// staging path only 2.9 TB/s vs m97's measured 13 TB/s on the same chip). 128²/4-wave
// blocks give ~4 independent blocks/CU -> m114 inter-block overlap hides barrier drain.
// Loop itself = r3's: counted vmcnt(4) (never 0 mid-loop), raw s_barrier + sched_barrier
// fences, setprio MFMA cluster, tile t+2 issued after trailing barrier (WAR-safe).
// MODE 0: h[slot, nb+n] = silu( xb[tok] @ w1t[e][nb+n][:] + b1 )   (K = 1024)
// MODE 1 (split-K=2): out[tok, nb+n] += p * ( h[slot] @ w2t[e][nb+n][:] + b2 )
// LDS [row][32] (64B rows): bank stripes alias every 2 rows -> XOR 16B-chunk with
// ((row>>1)&3): max 2-way aliasing = free (m136). r0's (row&3) was a true 4-way (8.9M).
// LDS[r][j] = glob[r][j ^ ((r>>1)&3)]; staging source chunk (l&3)^((l>>3)&3) per lane
// (call base rows ≡ 0 mod 16 so (row>>1)&3 == (l>>3)&3).
template <int MODE>
__global__ __launch_bounds__(256, 4) void k_gemm(
    const unsigned short* __restrict__ Abase,
    const unsigned short* __restrict__ Bt,
    const float* __restrict__ bias,
    const int* __restrict__ counts, const int* __restrict__ offs,
    const int* __restrict__ tbl_e, const int* __restrict__ tbl_m,
    const int* __restrict__ nblk,
    const int* __restrict__ lists_tok, const float* __restrict__ lists_p,
    unsigned short* __restrict__ hout, float* __restrict__ out,
    const int hb, const int Hs)
{
  const int bx = blockIdx.x;
  const int e  = tbl_e[bx];
  if (e < 0) return;
  const int m0  = tbl_m[bx];
  const int n_e = counts[e];
  const int by  = blockIdx.y;

  int nb, k0g, Kloc;
  if (MODE == 0) { nb = by << 7; k0g = 0; Kloc = DIM; }
  else { nb = (by >> 1) << 7; const int half = Hs >> 1;
         k0g = (by & 1) * half; Kloc = half; }

  const int tid  = threadIdx.x;
  const int lane = tid & 63;
  const int wv   = tid >> 6;                 // 0..3
  const int wm   = (wv & 1) << 6;            // 0 / 64
  const int wn   = (wv >> 1) << 6;           // 0 / 64

  __shared__ __align__(16) unsigned short as[2][128 * 32];  // 2 x 8 KB
  __shared__ __align__(16) unsigned short bs[2][128 * 32];  // 2 x 8 KB

  const int K = (MODE == 0) ? DIM : Hs;      // row stride of both A and B
  const unsigned short* Bexp = Bt + (size_t)e * ((size_t)DIM * Hs) + (size_t)nb * K + k0g;

  // staging: 4 gload_lds per wave per K-tile (2 A-halves + 2 B-halves of 16 rows).
  // call = 1 KB = 16 rows x 64 B; lane l -> row base+(l>>2), chunk l&3,
  // source chunk (l&3)^((l>>3)&3)  ->  LDS[r][j] = glob[r][j^((r>>1)&3)].
  const int off_sh = (((lane & 3) ^ ((lane >> 3) & 3)) << 3);   // shorts
  const int rA = (wv << 5) + (lane >> 2);               // wave band rows rA, rA+16
  const int rr0 = m0 + rA;
  const int rr1 = m0 + rA + 16;
  const int rc0 = (rr0 < n_e) ? rr0 : (n_e - 1);
  const int rc1 = (rr1 < n_e) ? rr1 : (n_e - 1);
  size_t arow0, arow1;
  if (MODE == 0) {
    arow0 = (size_t)lists_tok[e * NTOK + rc0] * DIM;
    arow1 = (size_t)lists_tok[e * NTOK + rc1] * DIM;
  } else {
    arow0 = (size_t)(offs[e] + rc0) * Hs;
    arow1 = (size_t)(offs[e] + rc1) * Hs;
  }
  const unsigned short* gpa0 = Abase + arow0 + k0g + off_sh;
  const unsigned short* gpa1 = Abase + arow1 + k0g + off_sh;
  const unsigned short* gpb0 = Bexp + (size_t)rA * K + off_sh;
  const unsigned short* gpb1 = Bexp + (size_t)(rA + 16) * K + off_sh;
  const int dbase = (wv << 5) * 32;                     // shorts; +16*32 for 2nd half

  auto issue = [&](int buf, int kk) {
    unsigned short* a0 = (buf ? &as[1][0] : &as[0][0]) + dbase;
    unsigned short* b0 = (buf ? &bs[1][0] : &bs[0][0]) + dbase;
    __builtin_amdgcn_global_load_lds(
        (const __attribute__((address_space(1))) void*)(gpa0 + kk),
        (__attribute__((address_space(3))) void*)(void*)a0, 16, 0, 0);
    __builtin_amdgcn_global_load_lds(
        (const __attribute__((address_space(1))) void*)(gpa1 + kk),
        (__attribute__((address_space(3))) void*)(void*)(a0 + 16 * 32), 16, 0, 0);
    __builtin_amdgcn_global_load_lds(
        (const __attribute__((address_space(1))) void*)(gpb0 + kk),
        (__attribute__((address_space(3))) void*)(void*)b0, 16, 0, 0);
    __builtin_amdgcn_global_load_lds(
        (const __attribute__((address_space(1))) void*)(gpb1 + kk),
        (__attribute__((address_space(3))) void*)(void*)(b0 + 16 * 32), 16, 0, 0);
  };

  floatx4 acc[4][4];
  #pragma unroll
  for (int i = 0; i < 4; ++i)
    #pragma unroll
    for (int j2 = 0; j2 < 4; ++j2) acc[i][j2] = (floatx4){0.f, 0.f, 0.f, 0.f};

  const int nt = Kloc >> 5;                  // K-tiles of 32
  issue(0, 0);
  issue(1, 32);
  int p = 0;
  for (int t = 0; t < nt; ++t) {
    // tile t complete; tile t+1's 4 calls stay in flight across the barrier (T4)
    if (t + 1 < nt) { asm volatile("s_waitcnt vmcnt(4)" ::: "memory"); }
    else            { asm volatile("s_waitcnt vmcnt(0)" ::: "memory"); }
    __builtin_amdgcn_sched_barrier(0);
    __builtin_amdgcn_s_barrier();
    __builtin_amdgcn_sched_barrier(0);
    const unsigned short* ap = p ? &as[1][0] : &as[0][0];
    const unsigned short* bp = p ? &bs[1][0] : &bs[0][0];
    const int c = lane >> 4;                 // logical 16B-chunk 0..3
    short8 af[4], bfr[4];
    #pragma unroll
    for (int i = 0; i < 4; ++i) {
      const int row = wm + (i << 4) + (lane & 15);
      af[i] = *(const short8*)(ap + (row << 5) + ((c ^ ((row >> 1) & 3)) << 3));
    }
    #pragma unroll
    for (int j2 = 0; j2 < 4; ++j2) {
      const int row = wn + (j2 << 4) + (lane & 15);
      bfr[j2] = *(const short8*)(bp + (row << 5) + ((c ^ ((row >> 1) & 3)) << 3));
    }
    __builtin_amdgcn_s_setprio(1);
    #pragma unroll
    for (int i = 0; i < 4; ++i)
      #pragma unroll
      for (int j2 = 0; j2 < 4; ++j2)
        acc[i][j2] = __builtin_amdgcn_mfma_f32_16x16x32_bf16(af[i], bfr[j2], acc[i][j2], 0, 0, 0);
    __builtin_amdgcn_s_setprio(0);
    __builtin_amdgcn_sched_barrier(0);
    __builtin_amdgcn_s_barrier();            // all waves done reading buf p
    __builtin_amdgcn_sched_barrier(0);
    if (t + 2 < nt) issue(p, (t + 2) << 5);  // overwrite tile t's buffer (safe)
    p ^= 1;
  }

  // epilogue: C/D map col=lane&15, row=(lane>>4)*4+rr (m89-verified)
  const int q4 = (lane >> 4) << 2;
  if (MODE == 0) {
    #pragma unroll
    for (int i = 0; i < 4; ++i) {
      #pragma unroll
      for (int j2 = 0; j2 < 4; ++j2) {
        const int nloc = wn + (j2 << 4) + (lane & 15);
        const float bb = bias[e * HID + hb + nb + nloc];
        #pragma unroll
        for (int rr = 0; rr < 4; ++rr) {
          const int m = m0 + wm + (i << 4) + q4 + rr;
          if (m < n_e) {
            float v = acc[i][j2][rr] + bb;
            v = v / (1.0f + __expf(-v));                 // silu
            hout[(size_t)(offs[e] + m) * Hs + nb + nloc] = f2bf(v);
          }
        }
      }
    }
  } else {
    #pragma unroll
    for (int i = 0; i < 4; ++i) {
      #pragma unroll
      for (int rr = 0; rr < 4; ++rr) {
        const int m = m0 + wm + (i << 4) + q4 + rr;
        if (m < n_e) {
          const int   tok = lists_tok[e * NTOK + m];
          const float pp  = lists_p[e * NTOK + m];
          #pragma unroll
          for (int j2 = 0; j2 < 4; ++j2) {
            const int d = nb + wn + (j2 << 4) + (lane & 15);
            float v = acc[i][j2][rr];
            if (hb == 0 && k0g == 0) v += bias[e * DIM + d];   // add b2 exactly once
            atomicAdd(out + (size_t)tok * DIM + d, pp * v);
          }
        }
      }
    }
  }
}

extern "C" void kernel_launch(void* const* d_in, const int* in_sizes, int n_in,
                              void* d_out, int out_size, void* d_ws, size_t ws_size,
                              hipStream_t stream)
{
  const float* x      = (const float*)d_in[0];
  const float* gate_w = (const float*)d_in[1];
  const float* gate_b = (const float*)d_in[2];
  const float* w1     = (const float*)d_in[3];
  const float* b1     = (const float*)d_in[4];
  const float* w2     = (const float*)d_in[5];
  const float* b2     = (const float*)d_in[6];
  const float* noise  = (const float*)d_in[7];
  float* out = (float*)d_out;

  char* ws = (char*)d_ws;
  const size_t CNT_OFF = 0;          // int counts[8]
  const size_t OFF_OFF = 64;         // int offs[9]
  const size_t NBK_OFF = 128;        // int nblk[1]
  const size_t TBE_OFF = 192;        // int tbl_e[144]
  const size_t TBM_OFF = 1024;       // int tbl_m[144]
  const size_t LT_OFF  = 4096;       // int  lists_tok[8][8192]   (256 KB)
  const size_t LP_OFF  = LT_OFF + 262144;
  const size_t PA_OFF  = LP_OFF + 262144;
  const size_t XB_OFF  = 1048576;    // bf16 xb[8192][1024]       (16 MB)
  const size_t W_OFF   = 17825792;   // bf16 weight-slice buffer  (32 MB / nsl), then h

  // pick H-slicing: need = W_OFF + 32MB/nsl (wt) + 64MB/nsl (h); Hs >= 256 required
  int nsl = 0;
  for (int cand = 1; cand <= 8; cand <<= 1) {
    const size_t need = W_OFF + (size_t)(33554432 + 67108864) / (size_t)cand;
    if (ws_size >= need) { nsl = cand; break; }
  }
  if (!nsl) return;
  const int Hs = HID / nsl;

  int* counts          = (int*)(ws + CNT_OFF);
  int* offs            = (int*)(ws + OFF_OFF);
  int* nblk            = (int*)(ws + NBK_OFF);
  int* tbl_e           = (int*)(ws + TBE_OFF);
  int* tbl_m           = (int*)(ws + TBM_OFF);
  int* lists_tok       = (int*)(ws + LT_OFF);
  float* lists_p       = (float*)(ws + LP_OFF);
  float* probs_all     = (float*)(ws + PA_OFF);
  unsigned short* xb   = (unsigned short*)(ws + XB_OFF);
  unsigned short* wt   = (unsigned short*)(ws + W_OFF);
  unsigned short* hbuf = (unsigned short*)(ws + W_OFF + (size_t)33554432 / nsl);

  hipMemsetAsync(d_out, 0, (size_t)OUT_MAIN * sizeof(float), stream);
  hipMemsetAsync(ws + CNT_OFF, 0, 64, stream);

  k_gating<<<NTOK / 16, 1024, 0, stream>>>(x, gate_w, gate_b, noise, out, counts,
                                           lists_tok, lists_p, probs_all, xb);
  k_meta<<<1, 256, 0, stream>>>(counts, offs, tbl_e, tbl_m, nblk, probs_all, out);

  for (int s = 0; s < nsl; ++s) {
    const int hb = s * Hs;
    // w1t slice: w1[e][d][h], rows d (1024), cols h in [hb,hb+Hs) -> wt[e][h'][d]
    dim3 gt1(DIM / 64, Hs / 64, NEXP);
    k_tr<<<gt1, 256, 0, stream>>>(w1, wt, HID, (size_t)DIM * HID, 0, hb,
                                  DIM, (size_t)Hs * DIM);
    dim3 g1(MAXBLK, Hs / 128, 1);
    k_gemm<0><<<g1, 256, 0, stream>>>(xb, wt, b1, counts, offs, tbl_e, tbl_m, nblk,
                                      lists_tok, lists_p, hbuf, out, hb, Hs);
    // w2t slice: w2[e][h][d], rows h in [hb,hb+Hs), cols d (1024) -> wt[e][d][h']
    dim3 gt2(Hs / 64, DIM / 64, NEXP);
    k_tr<<<gt2, 256, 0, stream>>>(w2, wt, DIM, (size_t)DIM * HID, hb, 0,
                                  Hs, (size_t)DIM * Hs);
    dim3 g2(MAXBLK, (DIM / 128) * 2, 1);   // x2 = split-K
    k_gemm<1><<<g2, 256, 0, stream>>>(hbuf, wt, b2, counts, offs, tbl_e, tbl_m, nblk,
                                      lists_tok, lists_p, hbuf, out, hb, Hs);
  }
}